// Round 1
// baseline (17105.507 us; speedup 1.0000x reference)
//
#include <hip/hip_runtime.h>
#include <hip/hip_fp16.h>
#include <math.h>

#define SEQ 512
#define ETA 0.1f
#define KAPPA 0.05f
#define AA 0.85f   /* 1 - ETA - KAPPA */

typedef _Float16 f16x8 __attribute__((ext_vector_type(8)));
typedef float f32x4 __attribute__((ext_vector_type(4)));

// workspace layout (float offsets)
#define WS_G    ((size_t)0)        /* 65536  G = B*B^T               */
#define WS_GD   ((size_t)65536)    /* 256    diag(G)                 */
#define WS_M0   ((size_t)65792)    /* 256    m0 = mean bubbles       */
#define WS_BX   ((size_t)66048)    /* 512*256 B*x_t                  */
#define WS_X2   ((size_t)197120)   /* 512    ||x_t||^2               */
#define WS_ZS   ((size_t)197632)   /* 512*256 d*Z                    */
#define WS_YS   ((size_t)328704)   /* 512*256 x + d*y                */
#define WS_GS   ((size_t)459776)   /* 4*512*256 g_1..g_4             */
#define WS_HS   ((size_t)984064)   /* 4*512   h_1..h_4               */
#define WS_ALS  ((size_t)986112)   /* 512*256 alpha_5                */
#define WS_BETS ((size_t)1117184)  /* 5*512*256 beta_5               */
#define WS_CT   ((size_t)1772544)  /* 512*5*256 c_0..c_4             */

__device__ __forceinline__ float wred_sum(float v) {
#pragma unroll
  for (int m = 1; m < 64; m <<= 1) v += __shfl_xor(v, m, 64);
  return v;
}
__device__ __forceinline__ float wred_min(float v) {
#pragma unroll
  for (int m = 1; m < 64; m <<= 1) v = fminf(v, __shfl_xor(v, m, 64));
  return v;
}
__device__ __forceinline__ float wred_max(float v) {
#pragma unroll
  for (int m = 1; m < 64; m <<= 1) v = fmaxf(v, __shfl_xor(v, m, 64));
  return v;
}

// ---------------- K0a: G = B B^T, Gd ----------------
__global__ void k0_gram(const float* __restrict__ B, float* __restrict__ ws) {
  float* G = ws + WS_G;
  float* Gd = ws + WS_GD;
  __shared__ float bi[256];
  const int i = blockIdx.x, j = threadIdx.x;
  bi[j] = B[(size_t)i * 256 + j];
  __syncthreads();
  float a0 = 0.f, a1 = 0.f, a2 = 0.f, a3 = 0.f;
#pragma unroll
  for (int c = 0; c < 256; c += 4) {
    float4 b4 = *(const float4*)&B[(size_t)j * 256 + c];
    a0 = fmaf(bi[c + 0], b4.x, a0);
    a1 = fmaf(bi[c + 1], b4.y, a1);
    a2 = fmaf(bi[c + 2], b4.z, a2);
    a3 = fmaf(bi[c + 3], b4.w, a3);
  }
  float acc = (a0 + a1) + (a2 + a3);
  G[(size_t)i * 256 + j] = acc;
  if (i == j) Gd[i] = acc;
}

// ---------------- K0c: m0 ----------------
__global__ void k0_m0(const float* __restrict__ B, float* __restrict__ ws) {
  float* M0 = ws + WS_M0;
  const int d = threadIdx.x;
  float acc = 0.f;
  for (int i = 0; i < 256; ++i) acc += B[(size_t)i * 256 + d];
  M0[d] = acc * (1.0f / 256.0f);
}

// ---------------- K0b: BX[t] = B x_t, X2[t] ----------------
__global__ void k0_bx(const float* __restrict__ B, const float* __restrict__ embed,
                      const int* __restrict__ toks, float* __restrict__ ws) {
  float* BX = ws + WS_BX;
  float* X2 = ws + WS_X2;
  __shared__ float xs[256];
  __shared__ float red[4];
  const int t = blockIdx.x, i = threadIdx.x;
  const int lane = i & 63, wid = i >> 6;
  const int tok = toks[t];
  float xv = embed[(size_t)tok * 256 + i];
  xs[i] = xv;
  float p = wred_sum(xv * xv);
  if (lane == 0) red[wid] = p;
  __syncthreads();
  if (i == 0) X2[t] = red[0] + red[1] + red[2] + red[3];
  float a0 = 0.f, a1 = 0.f, a2 = 0.f, a3 = 0.f;
#pragma unroll
  for (int c = 0; c < 256; c += 4) {
    float4 b4 = *(const float4*)&B[(size_t)i * 256 + c];
    a0 = fmaf(xs[c + 0], b4.x, a0);
    a1 = fmaf(xs[c + 1], b4.y, a1);
    a2 = fmaf(xs[c + 2], b4.z, a2);
    a3 = fmaf(xs[c + 3], b4.w, a3);
  }
  BX[(size_t)t * 256 + i] = (a0 + a1) + (a2 + a3);
}

// ---------------- K1: sequential scan in coefficient space ----------------
__global__ __launch_bounds__(256, 1) void k1_seq(
    const float* __restrict__ embed, const int* __restrict__ toks,
    const float* __restrict__ mdbp, const float* __restrict__ sensp,
    float* __restrict__ ws) {
  const int i = threadIdx.x;           // row index AND dim index
  const int lane = i & 63, wid = i >> 6;
  const float* G = ws + WS_G;
  const float* Gd = ws + WS_GD;
  const float* BX = ws + WS_BX;
  const float* X2 = ws + WS_X2;
  float* ZS = ws + WS_ZS;
  float* YS = ws + WS_YS;
  float* GS = ws + WS_GS;
  float* HS = ws + WS_HS;
  float* ALS = ws + WS_ALS;
  float* BETS = ws + WS_BETS;

  __shared__ __align__(16) float gls[6][256];
  __shared__ __align__(16) float qls[6][256];
  __shared__ __align__(16) float dp[8][256];
  __shared__ float dres[8];
  __shared__ float bmat[5][256];
  __shared__ float bbarls[5];
  __shared__ float xmmls[6];
  __shared__ float hls[6];

  // G row i held in VGPRs (G symmetric -> coalesced load of column i)
  float Grow[256];
#pragma unroll
  for (int j = 0; j < 256; ++j) Grow[j] = G[(size_t)j * 256 + i];
  const float Gdi = Gd[i];
  const float mdb = mdbp[0];
  const float sens = fabsf(sensp[0]);

  float Zi = 0.f, yi = 0.f, wi = 0.f, mm2 = 0.f;

  const int tok0 = toks[0];
  float x_c = embed[(size_t)tok0 * 256 + i];
  float bx_c = BX[i];
  float x2_c = X2[0];

#pragma unroll 1
  for (int t = 0; t < SEQ; ++t) {
    // prefetch next step's token data
    const int tn = (t + 1 < SEQ) ? (t + 1) : t;
    const int tokn = toks[tn];
    const float x_n = embed[(size_t)tokn * 256 + i];
    const float bx_n = BX[(size_t)tn * 256 + i];
    const float x2_n = X2[tn];

    // <x, mem_mean> with mem_mean = B^T Z + y
    dp[0][i] = bx_c * Zi + x_c * yi;
    __syncthreads();
    if (wid == 0) {
      float v = dp[0][lane] + dp[0][lane + 64] + dp[0][lane + 128] + dp[0][lane + 192];
      v = wred_sum(v);
      if (lane == 0) dres[0] = v;
    }
    __syncthreads();
    const float dotxm = dres[0];
    const float memnorm = sqrtf(fmaxf(mm2, 0.f)) + 1e-10f;
    const float xnorm = sqrtf(x2_c) + 1e-10f;
    const float nov = (memnorm > 1e-8f) ? (1.0f - dotxm / (xnorm * memnorm)) : 1.0f;
    const float dec = 1.0f / (1.0f + expf(-(mdb - sens * nov)));
    const float ri = bx_c + dec * wi;                       // r = B xm
    const float XM2 = x2_c + 2.f * dec * dotxm + dec * dec * mm2;
    ZS[(size_t)t * 256 + i] = dec * Zi;                     // xm = ys + B^T Zs
    YS[(size_t)t * 256 + i] = x_c + dec * yi;

    float alpha = 1.0f;
    float qk_final = 0.f, g5i = 0.f, h5 = 0.f;

#pragma unroll 1
    for (int k = 0; k <= 5; ++k) {
      // m_k = B^T g_k + h_k xm
      float hk, gki;
      if (k == 0) {
        hk = 0.f;
        gki = 1.0f / 256.0f;
      } else {
        hk = 0.f;
        gki = alpha * (1.0f / 256.0f);
        for (int l = 0; l < k; ++l) {
          hk += bbarls[l] * (ETA + KAPPA * hls[l]);
          gki += KAPPA * bbarls[l] * gls[l][i];
        }
      }
      gls[k][i] = gki;
      if (i == 0) hls[k] = hk;
      if (k >= 1 && k <= 4) {
        GS[(size_t)(k - 1) * (SEQ * 256) + (size_t)t * 256 + i] = gki;
        if (i == 0) HS[(size_t)(k - 1) * SEQ + t] = hk;
      }
      __syncthreads();  // A: g_k visible
      // q_k = G g_k + h_k r   (= B m_k)
      float a0 = 0.f, a1 = 0.f, a2 = 0.f, a3 = 0.f;
      const float4* g4p = (const float4*)&gls[k][0];
#pragma unroll
      for (int j4 = 0; j4 < 64; ++j4) {
        float4 g4 = g4p[j4];
        a0 = fmaf(Grow[4 * j4 + 0], g4.x, a0);
        a1 = fmaf(Grow[4 * j4 + 1], g4.y, a1);
        a2 = fmaf(Grow[4 * j4 + 2], g4.z, a2);
        a3 = fmaf(Grow[4 * j4 + 3], g4.w, a3);
      }
      const float qk = (a0 + a1) + (a2 + a3) + hk * ri;
      qls[k][i] = qk;
      for (int l = 0; l < k; ++l) dp[l][i] = gki * qls[l][i];
      dp[k][i] = gki * qk;
      dp[k + 1][i] = ri * gki;
      int nv = k + 2;
      if (k == 5) { dp[7][i] = wi * gki; nv = 8; }
      __syncthreads();  // B
      for (int l = wid; l < nv; l += 4) {
        float v = dp[l][lane] + dp[l][lane + 64] + dp[l][lane + 128] + dp[l][lane + 192];
        v = wred_sum(v);
        if (lane == 0) dres[l] = v;
      }
      __syncthreads();  // C
      if (k < 5) {
        const float xmmk = dres[k + 1] + hk * XM2;          // <xm, m_k>
        const float tki = ETA * ri + KAPPA * qk;            // <B_i, c_k>
        float sc = alpha * tki;                             // <s_k[i], c_k>
        for (int jj = 0; jj < k; ++jj) {
          const float xmmj = xmmls[jj];
          const float MMjk = dres[jj] + hk * xmmj;          // <m_k, m_j>
          const float CCjk = (ETA * ETA) * XM2 + (ETA * KAPPA) * (xmmj + xmmk) +
                             (KAPPA * KAPPA) * MMjk;        // <c_j, c_k>
          sc += bmat[jj][i] * CCjk;
        }
        const float MMkk = dres[k] + hk * xmmk;
        const float CCkk = (ETA * ETA) * XM2 + 2.f * (ETA * KAPPA) * xmmk +
                           (KAPPA * KAPPA) * MMkk;
        const float ssq = (k == 0) ? Gdi : 1.0f;            // ||s_k[i]||^2
        const float n2 = fmaxf(AA * AA * ssq + 2.f * AA * sc + CCkk, 0.f);
        const float nn = sqrtf(n2) + 1e-10f;
        const float inv = 1.0f / nn;
        for (int jj = 0; jj < k; ++jj) bmat[jj][i] *= (AA * inv);
        bmat[k][i] = inv;
        alpha *= AA * inv;
        if (i == 0) xmmls[k] = xmmk;
        __syncthreads();  // D: bmat visible
        for (int l = wid; l <= k; l += 4) {
          float v = bmat[l][lane] + bmat[l][lane + 64] + bmat[l][lane + 128] + bmat[l][lane + 192];
          v = wred_sum(v);
          if (lane == 0) bbarls[l] = v * (1.0f / 256.0f);
        }
        __syncthreads();  // E: bbar visible
      } else {
        qk_final = qk;  // B m_5
        g5i = gki;
        h5 = hk;
      }
    }
    // state update: mem' = dec*mem + (1-dec)*m5, m5 = B^T g5 + h5 xm
    const float xmm5 = dres[6] + h5 * XM2;
    const float m52 = dres[5] + h5 * xmm5;
    const float cmm5 = dres[7] + h5 * (dotxm + dec * mm2);
    const float lamc = dec * (1.0f + (1.0f - dec) * h5);
    Zi = lamc * Zi + (1.0f - dec) * g5i;
    yi = lamc * yi + (1.0f - dec) * h5 * x_c;
    wi = dec * wi + (1.0f - dec) * qk_final;
    mm2 = fmaxf(dec * dec * mm2 + 2.f * dec * (1.f - dec) * cmm5 +
                    (1.f - dec) * (1.f - dec) * m52, 0.f);
    ALS[(size_t)t * 256 + i] = alpha;
#pragma unroll
    for (int j = 0; j < 5; ++j)
      BETS[(size_t)j * (SEQ * 256) + (size_t)t * 256 + i] = bmat[j][i];
    x_c = x_n; bx_c = bx_n; x2_c = x2_n;
  }
}

// ---------------- K15: materialize xm and c_0..c_4 per step ----------------
__global__ void k15_cvec(const float* __restrict__ B, float* __restrict__ ws) {
  const float* ZS = ws + WS_ZS;
  const float* YS = ws + WS_YS;
  const float* GS = ws + WS_GS;
  const float* HS = ws + WS_HS;
  const float* M0 = ws + WS_M0;
  float* CT = ws + WS_CT;
  const int t = blockIdx.x, d = threadIdx.x;
  __shared__ float zs[256], g1[256], g2[256], g3[256], g4[256];
  zs[d] = ZS[(size_t)t * 256 + d];
  g1[d] = GS[0 * (SEQ * 256) + (size_t)t * 256 + d];
  g2[d] = GS[1 * (SEQ * 256) + (size_t)t * 256 + d];
  g3[d] = GS[2 * (SEQ * 256) + (size_t)t * 256 + d];
  g4[d] = GS[3 * (SEQ * 256) + (size_t)t * 256 + d];
  __syncthreads();
  float xa = 0.f, b1 = 0.f, b2 = 0.f, b3 = 0.f, b4 = 0.f;
  for (int ii = 0; ii < 256; ++ii) {
    const float Bv = B[(size_t)ii * 256 + d];
    xa = fmaf(zs[ii], Bv, xa);
    b1 = fmaf(g1[ii], Bv, b1);
    b2 = fmaf(g2[ii], Bv, b2);
    b3 = fmaf(g3[ii], Bv, b3);
    b4 = fmaf(g4[ii], Bv, b4);
  }
  const float xm = YS[(size_t)t * 256 + d] + xa;
  float* ctt = CT + (size_t)t * 1280;
  ctt[0 * 256 + d] = ETA * xm + KAPPA * M0[d];
  const float h1 = HS[0 * SEQ + t], h2 = HS[1 * SEQ + t];
  const float h3 = HS[2 * SEQ + t], h4 = HS[3 * SEQ + t];
  ctt[1 * 256 + d] = (ETA + KAPPA * h1) * xm + KAPPA * b1;
  ctt[2 * 256 + d] = (ETA + KAPPA * h2) * xm + KAPPA * b2;
  ctt[3 * 256 + d] = (ETA + KAPPA * h3) * xm + KAPPA * b3;
  ctt[4 * 256 + d] = (ETA + KAPPA * h4) * xm + KAPPA * b4;
}

// ---------------- K2: per-step rho -> eigenvalues ----------------
__global__ __launch_bounds__(1024, 4) void k2_eig(
    const float* __restrict__ B, const float* __restrict__ ws,
    float* __restrict__ out) {
  const int t = blockIdx.x;
  const int tid = threadIdx.x;
  const int lane = tid & 63, wid = tid >> 6;
  const float* CT = ws + WS_CT + (size_t)t * 1280;
  const float* ALS = ws + WS_ALS + (size_t)t * 256;
  const float* BETS = ws + WS_BETS;

  __shared__ __align__(16) unsigned char bigbuf[135168];  // sT fp16 [256][264] / packed rho fp32
  _Float16* sT = (_Float16*)bigbuf;
  float* pk = (float*)bigbuf;
  __shared__ __align__(16) float ct[1280];
  __shared__ float vx[256], pv[256], qv[256];
  __shared__ float dd[256], ee[256], e2[256], lamv[256];
  __shared__ float red[16];

  for (int idx = tid; idx < 1280; idx += 1024) ct[idx] = CT[idx];
  __syncthreads();

  // --- regenerate s5 rows, store transposed fp16 ---
  {
    const int r = tid >> 2, q = tid & 3;
    const float al = ALS[r];
    const float be0 = BETS[(size_t)0 * (SEQ * 256) + (size_t)t * 256 + r];
    const float be1 = BETS[(size_t)1 * (SEQ * 256) + (size_t)t * 256 + r];
    const float be2 = BETS[(size_t)2 * (SEQ * 256) + (size_t)t * 256 + r];
    const float be3 = BETS[(size_t)3 * (SEQ * 256) + (size_t)t * 256 + r];
    const float be4 = BETS[(size_t)4 * (SEQ * 256) + (size_t)t * 256 + r];
#pragma unroll
    for (int j4 = 0; j4 < 16; ++j4) {
      const int d0 = q * 64 + j4 * 4;
      const float4 Bv = *(const float4*)&B[(size_t)r * 256 + d0];
      const float4 c0 = *(const float4*)&ct[0 * 256 + d0];
      const float4 c1 = *(const float4*)&ct[1 * 256 + d0];
      const float4 c2 = *(const float4*)&ct[2 * 256 + d0];
      const float4 c3 = *(const float4*)&ct[3 * 256 + d0];
      const float4 c4 = *(const float4*)&ct[4 * 256 + d0];
      const float s0 = al * Bv.x + be0 * c0.x + be1 * c1.x + be2 * c2.x + be3 * c3.x + be4 * c4.x;
      const float s1 = al * Bv.y + be0 * c0.y + be1 * c1.y + be2 * c2.y + be3 * c3.y + be4 * c4.y;
      const float s2 = al * Bv.z + be0 * c0.z + be1 * c1.z + be2 * c2.z + be3 * c3.z + be4 * c4.z;
      const float s3 = al * Bv.w + be0 * c0.w + be1 * c1.w + be2 * c2.w + be3 * c3.w + be4 * c4.w;
      sT[(size_t)(d0 + 0) * 264 + r] = (_Float16)s0;
      sT[(size_t)(d0 + 1) * 264 + r] = (_Float16)s1;
      sT[(size_t)(d0 + 2) * 264 + r] = (_Float16)s2;
      sT[(size_t)(d0 + 3) * 264 + r] = (_Float16)s3;
    }
  }
  __syncthreads();

  // --- rho = sT * sT^T / 256 via MFMA f16 (4x4 tiles of 16x16 per wave) ---
  f32x4 acc[4][4];
#pragma unroll
  for (int ti = 0; ti < 4; ++ti)
#pragma unroll
    for (int tj = 0; tj < 4; ++tj) {
      f32x4 z = {0.f, 0.f, 0.f, 0.f};
      acc[ti][tj] = z;
    }
  {
    const int Ib = (wid >> 2) * 4, Jb = (wid & 3) * 4;
    const int mr = lane & 15, kg = lane >> 4;  // A[m=lane&15][k=(lane>>4)*8+j]
#pragma unroll 1
    for (int kb = 0; kb < 8; ++kb) {
      const int ko = kb * 32 + kg * 8;
      f16x8 aF[4], bF[4];
#pragma unroll
      for (int ti = 0; ti < 4; ++ti)
        aF[ti] = *(const f16x8*)&sT[(size_t)((Ib + ti) * 16 + mr) * 264 + ko];
#pragma unroll
      for (int tj = 0; tj < 4; ++tj)
        bF[tj] = *(const f16x8*)&sT[(size_t)((Jb + tj) * 16 + mr) * 264 + ko];
#pragma unroll
      for (int ti = 0; ti < 4; ++ti)
#pragma unroll
        for (int tj = 0; tj < 4; ++tj)
          acc[ti][tj] = __builtin_amdgcn_mfma_f32_16x16x32_f16(aF[ti], bF[tj], acc[ti][tj], 0, 0, 0);
    }
  }
  __syncthreads();  // all fragment reads from sT complete before aliasing writes
  {
    const int Ib = (wid >> 2) * 4, Jb = (wid & 3) * 4;
    const int cn = lane & 15, rg = lane >> 4;  // C/D: col=lane&15, row=(lane>>4)*4+reg
#pragma unroll
    for (int ti = 0; ti < 4; ++ti)
#pragma unroll
      for (int tj = 0; tj < 4; ++tj) {
        const int C = (Jb + tj) * 16 + cn;
        const int Rb = (Ib + ti) * 16 + rg * 4;
#pragma unroll
        for (int rr = 0; rr < 4; ++rr) {
          const int R = Rb + rr;
          if (R >= C) pk[R * (R + 1) / 2 + C] = acc[ti][tj][rr] * (1.0f / 256.0f);
        }
      }
  }
  __syncthreads();

  // --- Householder tridiagonalization on packed lower fp32 ---
#pragma unroll 1
  for (int j = 0; j < 254; ++j) {
    const int m = 255 - j;
    const float x0 = pk[(j + 1) * (j + 2) / 2 + j];
    float ps = 0.f;
    if (tid < m) {
      const int gr = j + 1 + tid;
      const float xv_ = pk[gr * (gr + 1) / 2 + j];
      vx[tid] = xv_;
      ps = xv_ * xv_;
    }
    ps = wred_sum(ps);
    if (lane == 0) red[wid] = ps;
    __syncthreads();  // T1
    float sig2 = 0.f;
#pragma unroll
    for (int w = 0; w < 16; ++w) sig2 += red[w];
    const float sig = sqrtf(sig2);
    const float sg = (x0 >= 0.f) ? 1.f : -1.f;
    const bool live = (sig2 > 1e-26f);
    const float beta = live ? (1.0f / (sig * (sig + fabsf(x0)))) : 0.f;
    const float v0 = live ? (x0 + sg * sig) : 0.f;
    if (tid == 0) {
      dd[j] = pk[j * (j + 1) / 2 + j];
      ee[j] = live ? (-sg * sig) : x0;
      vx[0] = v0;
    }
    __syncthreads();  // T2
    // pv = A22 * v (symmetric packed matvec; quad of threads per row)
    {
      const int ri_ = tid >> 2, qd = tid & 3;
      float acc2 = 0.f;
      if (ri_ < m) {
        const int gr = j + 1 + ri_;
        const int c0 = (m * qd) >> 2, c1 = (m * (qd + 1)) >> 2;
        const int rowbase = gr * (gr + 1) / 2 + (j + 1);
        const int clend = min(c1, ri_ + 1);
        for (int c = c0; c < clend; ++c) acc2 = fmaf(pk[rowbase + c], vx[c], acc2);
        const int cu = max(c0, ri_ + 1);
        if (cu < c1) {
          int gc = j + 1 + cu;
          int ub = gc * (gc + 1) / 2 + gr;
          int stp = gc + 1;
          for (int c = cu; c < c1; ++c) { acc2 = fmaf(pk[ub], vx[c], acc2); ub += stp; ++stp; }
        }
      }
      acc2 += __shfl_xor(acc2, 1, 64);
      acc2 += __shfl_xor(acc2, 2, 64);
      float vpp = 0.f;
      if ((tid & 3) == 0 && (tid >> 2) < m) { pv[tid >> 2] = acc2; vpp = acc2 * vx[tid >> 2]; }
      vpp = wred_sum(vpp);
      if (lane == 0) red[wid] = vpp;
    }
    __syncthreads();  // T3
    float vtp = 0.f;
#pragma unroll
    for (int w = 0; w < 16; ++w) vtp += red[w];
    const float gamma = 0.5f * beta * beta * vtp;
    if (tid < m) qv[tid] = beta * pv[tid] - gamma * vx[tid];
    __syncthreads();  // T4
    // rank-2 update A22 -= v q^T + q v^T (lower packed, paired rows for balance)
    {
      const int Q = tid >> 2, qd = tid & 3;
      const int i2 = m - 1 - Q;
      if (Q <= i2 && Q < m) {
        {
          const int gr = j + 1 + Q;
          const int rb = gr * (gr + 1) / 2 + (j + 1);
          const float vi = vx[Q], qi = qv[Q];
          const int cs = (qd * (Q + 1)) >> 2, ce = ((qd + 1) * (Q + 1)) >> 2;
          for (int c = cs; c < ce; ++c) pk[rb + c] -= vi * qv[c] + qi * vx[c];
        }
        if (i2 > Q) {
          const int gr = j + 1 + i2;
          const int rb = gr * (gr + 1) / 2 + (j + 1);
          const float vi = vx[i2], qi = qv[i2];
          const int cs = (qd * (i2 + 1)) >> 2, ce = ((qd + 1) * (i2 + 1)) >> 2;
          for (int c = cs; c < ce; ++c) pk[rb + c] -= vi * qv[c] + qi * vx[c];
        }
      }
    }
    __syncthreads();  // T5
  }
  if (tid == 0) {
    dd[254] = pk[254 * 255 / 2 + 254];
    dd[255] = pk[255 * 256 / 2 + 255];
    ee[254] = pk[255 * 256 / 2 + 254];
    ee[255] = 0.f;
  }
  __syncthreads();
  if (tid < 256) e2[tid] = ee[tid] * ee[tid];
  __syncthreads();
  // Gershgorin bounds
  float glo = 1e30f, ghi = -1e30f;
  if (tid < 256) {
    const float rad = fabsf(ee[tid]) + ((tid > 0) ? fabsf(ee[tid - 1]) : 0.f);
    glo = dd[tid] - rad;
    ghi = dd[tid] + rad;
  }
  {
    float v = wred_min(glo);
    if (lane == 0) red[wid] = v;
    __syncthreads();
    float lo0 = 1e30f;
#pragma unroll
    for (int w = 0; w < 16; ++w) lo0 = fminf(lo0, red[w]);
    __syncthreads();
    v = wred_max(ghi);
    if (lane == 0) red[wid] = v;
    __syncthreads();
    float hi0 = -1e30f;
#pragma unroll
    for (int w = 0; w < 16; ++w) hi0 = fmaxf(hi0, red[w]);
    lo0 -= 1e-3f + 1e-3f * fabsf(lo0);
    hi0 += 1e-3f + 1e-3f * fabsf(hi0);
    // Sturm bisection: thread k -> k-th smallest eigenvalue
    if (tid < 256) {
      float lo = lo0, hi = hi0;
      for (int it = 0; it < 21; ++it) {
        const float x = 0.5f * (lo + hi);
        int cnt = 0;
        float qq = dd[0] - x;
        cnt += (qq < 0.f);
        for (int ii = 1; ii < 256; ++ii) {
          float dn = qq;
          if (fabsf(dn) < 1e-25f) dn = (dn < 0.f) ? -1e-25f : 1e-25f;
          qq = (dd[ii] - x) - e2[ii - 1] * __builtin_amdgcn_rcpf(dn);
          cnt += (qq < 0.f);
        }
        if (cnt >= tid + 1) hi = x; else lo = x;
      }
      lamv[tid] = fmaxf(0.5f * (lo + hi), 0.f);
    }
  }
  __syncthreads();
  float sv = (tid < 256) ? lamv[tid] : 0.f;
  sv = wred_sum(sv);
  if (lane == 0) red[wid] = sv;
  __syncthreads();
  float S = 0.f;
#pragma unroll
  for (int w = 0; w < 16; ++w) S += red[w];
  if (tid < 256) out[(size_t)t * 256 + tid] = lamv[tid] / (S + 1e-10f);
}

extern "C" void kernel_launch(void* const* d_in, const int* in_sizes, int n_in,
                              void* d_out, int out_size, void* d_ws, size_t ws_size,
                              hipStream_t stream) {
  const float* embed = (const float*)d_in[0];
  const float* B = (const float*)d_in[1];
  const float* mdb = (const float*)d_in[2];
  const float* sens = (const float*)d_in[3];
  const int* toks = (const int*)d_in[4];
  float* out = (float*)d_out;
  float* ws = (float*)d_ws;

  k0_gram<<<dim3(256), dim3(256), 0, stream>>>(B, ws);
  k0_m0<<<dim3(1), dim3(256), 0, stream>>>(B, ws);
  k0_bx<<<dim3(SEQ), dim3(256), 0, stream>>>(B, embed, toks, ws);
  k1_seq<<<dim3(1), dim3(256), 0, stream>>>(embed, toks, mdb, sens, ws);
  k15_cvec<<<dim3(SEQ), dim3(256), 0, stream>>>(B, ws);
  k2_eig<<<dim3(SEQ), dim3(1024), 0, stream>>>(B, ws, out);
}

// Round 2
// 9853.568 us; speedup vs baseline: 1.7360x; 1.7360x over previous
//
#include <hip/hip_runtime.h>
#include <hip/hip_fp16.h>
#include <math.h>

#define SEQ 512
#define ETA 0.1f
#define KAPPA 0.05f
#define AA 0.85f   /* 1 - ETA - KAPPA */

typedef _Float16 f16x8 __attribute__((ext_vector_type(8)));
typedef float f32x4 __attribute__((ext_vector_type(4)));

// workspace layout (float offsets) -- identical footprint to round 1
#define WS_G    ((size_t)0)        /* 65536  G = B*B^T               */
#define WS_GD   ((size_t)65536)    /* 256    diag(G)                 */
#define WS_M0   ((size_t)65792)    /* 256    m0 = mean bubbles       */
#define WS_BX   ((size_t)66048)    /* 512*256 B*x_t                  */
#define WS_X2   ((size_t)197120)   /* 512    ||x_t||^2               */
#define WS_ZS   ((size_t)197632)   /* 512*256 d*Z                    */
#define WS_YS   ((size_t)328704)   /* 512*256 x + d*y                */
#define WS_GS   ((size_t)459776)   /* 4*512*256 g_1..g_4             */
#define WS_HS   ((size_t)984064)   /* 4*512   h_1..h_4               */
#define WS_ALS  ((size_t)986112)   /* 512*256 alpha_5                */
#define WS_BETS ((size_t)1117184)  /* 5*512*256 beta_5               */
#define WS_CT   ((size_t)1772544)  /* 512*5*256 c_0..c_4             */

__device__ __forceinline__ float wred_sum(float v) {
#pragma unroll
  for (int m = 1; m < 64; m <<= 1) v += __shfl_xor(v, m, 64);
  return v;
}
__device__ __forceinline__ float wred_min(float v) {
#pragma unroll
  for (int m = 1; m < 64; m <<= 1) v = fminf(v, __shfl_xor(v, m, 64));
  return v;
}
__device__ __forceinline__ float wred_max(float v) {
#pragma unroll
  for (int m = 1; m < 64; m <<= 1) v = fmaxf(v, __shfl_xor(v, m, 64));
  return v;
}
__device__ __forceinline__ float rfl(float x) {
  return __builtin_bit_cast(float, __builtin_amdgcn_readfirstlane(__builtin_bit_cast(int, x)));
}

// ---------------- K0a: G = B B^T, Gd ----------------
__global__ void k0_gram(const float* __restrict__ B, float* __restrict__ ws) {
  float* G = ws + WS_G;
  float* Gd = ws + WS_GD;
  __shared__ float bi[256];
  const int i = blockIdx.x, j = threadIdx.x;
  bi[j] = B[(size_t)i * 256 + j];
  __syncthreads();
  float a0 = 0.f, a1 = 0.f, a2 = 0.f, a3 = 0.f;
#pragma unroll
  for (int c = 0; c < 256; c += 4) {
    float4 b4 = *(const float4*)&B[(size_t)j * 256 + c];
    a0 = fmaf(bi[c + 0], b4.x, a0);
    a1 = fmaf(bi[c + 1], b4.y, a1);
    a2 = fmaf(bi[c + 2], b4.z, a2);
    a3 = fmaf(bi[c + 3], b4.w, a3);
  }
  float acc = (a0 + a1) + (a2 + a3);
  G[(size_t)i * 256 + j] = acc;
  if (i == j) Gd[i] = acc;
}

// ---------------- K0c: m0 ----------------
__global__ void k0_m0(const float* __restrict__ B, float* __restrict__ ws) {
  float* M0 = ws + WS_M0;
  const int d = threadIdx.x;
  float acc = 0.f;
  for (int i = 0; i < 256; ++i) acc += B[(size_t)i * 256 + d];
  M0[d] = acc * (1.0f / 256.0f);
}

// ---------------- K0b: BX[t] = B x_t, X2[t] ----------------
__global__ void k0_bx(const float* __restrict__ B, const float* __restrict__ embed,
                      const int* __restrict__ toks, float* __restrict__ ws) {
  float* BX = ws + WS_BX;
  float* X2 = ws + WS_X2;
  __shared__ float xs[256];
  __shared__ float red[4];
  const int t = blockIdx.x, i = threadIdx.x;
  const int lane = i & 63, wid = i >> 6;
  const int tok = toks[t];
  float xv = embed[(size_t)tok * 256 + i];
  xs[i] = xv;
  float p = wred_sum(xv * xv);
  if (lane == 0) red[wid] = p;
  __syncthreads();
  if (i == 0) X2[t] = red[0] + red[1] + red[2] + red[3];
  float a0 = 0.f, a1 = 0.f, a2 = 0.f, a3 = 0.f;
#pragma unroll
  for (int c = 0; c < 256; c += 4) {
    float4 b4 = *(const float4*)&B[(size_t)i * 256 + c];
    a0 = fmaf(xs[c + 0], b4.x, a0);
    a1 = fmaf(xs[c + 1], b4.y, a1);
    a2 = fmaf(xs[c + 2], b4.z, a2);
    a3 = fmaf(xs[c + 3], b4.w, a3);
  }
  BX[(size_t)t * 256 + i] = (a0 + a1) + (a2 + a3);
}

// ---------------- K1: sequential scan, G split across 2 threads/row ----------------
// 512 threads: i = tid>>1 (row/dim), h = tid&1 (half of the dot product).
// Gq[128] stays in VGPRs (no spill). Per-i histories replicated across h in regs.
__global__ __launch_bounds__(512, 1) void k1_seq(
    const float* __restrict__ embed, const int* __restrict__ toks,
    const float* __restrict__ mdbp, const float* __restrict__ sensp,
    float* __restrict__ ws) {
  const int tid = threadIdx.x;
  const int lane = tid & 63, wave = tid >> 6;
  const int i = tid >> 1, h = tid & 1;
  const float* G = ws + WS_G;
  const float* Gd = ws + WS_GD;
  const float* BX = ws + WS_BX;
  const float* X2 = ws + WS_X2;
  float* ZS = ws + WS_ZS;
  float* YS = ws + WS_YS;
  float* GS = ws + WS_GS;
  float* HS = ws + WS_HS;
  float* ALS = ws + WS_ALS;
  float* BETS = ws + WS_BETS;

  __shared__ __align__(16) float gcur[256];
  __shared__ __align__(16) float dp[6][256];
  __shared__ float dres_s[8];
  __shared__ float bbar_s[8];

  // half G-row in VGPRs
  float Gq[128];
  {
    const float4* gr = (const float4*)(G + (size_t)i * 256 + (size_t)h * 128);
#pragma unroll
    for (int j4 = 0; j4 < 32; ++j4) {
      float4 v = gr[j4];
      Gq[4 * j4 + 0] = v.x; Gq[4 * j4 + 1] = v.y;
      Gq[4 * j4 + 2] = v.z; Gq[4 * j4 + 3] = v.w;
    }
  }
  const float Gdi = Gd[i];
  const float mdb = rfl(mdbp[0]);
  const float sens = fabsf(rfl(sensp[0]));

  // q0 = G * (1/256) is constant across t
  float q0i;
  {
    float s = 0.f;
#pragma unroll
    for (int j = 0; j < 128; ++j) s += Gq[j];
    s += __shfl_xor(s, 1, 64);
    q0i = s * (1.0f / 256.0f);
  }
  // preamble reductions: c00 = <g0,q0>, mbx_c = mean(BX[0])
  float x_c = embed[(size_t)toks[0] * 256 + i];
  float bx_c = BX[i];
  float x2_c = rfl(X2[0]);
  if (h == 0) dp[0][i] = q0i; else dp[1][i] = bx_c;
  __syncthreads();
  if (wave < 2) {
    float4 v4 = ((const float4*)&dp[wave][0])[lane];
    float r_ = (v4.x + v4.y) + (v4.z + v4.w);
    r_ = wred_sum(r_);
    if (lane == 0) dres_s[wave] = r_ * (1.0f / 256.0f);
  }
  __syncthreads();
  const float c00 = rfl(dres_s[0]);
  float mbx_c = rfl(dres_s[1]);

  float Zi = 0.f, yi = 0.f, wi = 0.f;
  float mm2 = 0.f, mw = 0.f, dotxm = 0.f;

#pragma unroll 1
  for (int t = 0; t < SEQ; ++t) {
    const int tn = (t + 1 < SEQ) ? (t + 1) : t;
    const int tokn = toks[tn];
    const float x_n = embed[(size_t)tokn * 256 + i];
    const float bx_n = BX[(size_t)tn * 256 + i];
    const float x2_n = rfl(X2[tn]);

    const float memnorm = sqrtf(fmaxf(mm2, 0.f)) + 1e-10f;
    const float xnorm = sqrtf(x2_c) + 1e-10f;
    const float nov = (memnorm > 1e-8f) ? (1.0f - dotxm / (xnorm * memnorm)) : 1.0f;
    const float dec = 1.0f / (1.0f + expf(-(mdb - sens * nov)));
    const float od = 1.0f - dec;
    const float ri = bx_c + dec * wi;
    const float XM2 = x2_c + 2.f * dec * dotxm + dec * dec * mm2;
    const float mean_r = mbx_c + dec * mw;
    if (h == 0) ZS[(size_t)t * 256 + i] = dec * Zi;
    else        YS[(size_t)t * 256 + i] = x_c + dec * yi;

    float qhist[6], ghist[6], bmat[5], hls[6], xmm[5], bbar[5];
    float alpha;
    // ---- k = 0: no matvec, no dot round (q0, c00, mean_r precomputed) ----
    {
      qhist[0] = q0i; ghist[0] = 1.0f / 256.0f; hls[0] = 0.f;
      const float xmm0 = mean_r;
      const float tki = ETA * ri + KAPPA * q0i;
      const float CC00 = (ETA * ETA) * XM2 + 2.f * (ETA * KAPPA) * xmm0 +
                         (KAPPA * KAPPA) * c00;
      const float n2 = fmaxf(AA * AA * Gdi + 2.f * AA * tki + CC00, 0.f);
      const float inv = 1.0f / (sqrtf(n2) + 1e-10f);
      bmat[0] = inv; alpha = AA * inv; xmm[0] = xmm0;
      if (h == 0) dp[0][i] = inv;
    }
    __syncthreads();  // D0
    if (wave == 0) {
      float4 v4 = ((const float4*)&dp[0][0])[lane];
      float r_ = (v4.x + v4.y) + (v4.z + v4.w);
      r_ = wred_sum(r_);
      if (lane == 0) bbar_s[0] = r_ * (1.0f / 256.0f);
    }
    __syncthreads();  // E0
    bbar[0] = rfl(bbar_s[0]);

    // ---- k = 1..5 ----
#pragma unroll
    for (int k = 1; k <= 5; ++k) {
      float hk = 0.f, gk = alpha * (1.0f / 256.0f);
#pragma unroll
      for (int l = 0; l < 5; ++l)
        if (l < k) {
          hk += bbar[l] * (ETA + KAPPA * hls[l]);
          gk += KAPPA * bbar[l] * ghist[l];
        }
      ghist[k] = gk; hls[k] = hk;
      if (k <= 4) {
        if (h == 0) GS[(size_t)(k - 1) * (SEQ * 256) + (size_t)t * 256 + i] = gk;
        if (tid == 0) HS[(size_t)(k - 1) * SEQ + t] = hk;
      }
      if (h == 0) gcur[i] = gk;
      __syncthreads();  // A
      // q_k = G g_k + h_k r
      float a0 = 0.f, a1 = 0.f, a2 = 0.f, a3 = 0.f;
      const float4* gseg = (const float4*)&gcur[h * 128];
#pragma unroll
      for (int j4 = 0; j4 < 32; ++j4) {
        float4 g4 = gseg[j4];
        a0 = fmaf(Gq[4 * j4 + 0], g4.x, a0);
        a1 = fmaf(Gq[4 * j4 + 1], g4.y, a1);
        a2 = fmaf(Gq[4 * j4 + 2], g4.z, a2);
        a3 = fmaf(Gq[4 * j4 + 3], g4.w, a3);
      }
      float acc = (a0 + a1) + (a2 + a3);
      acc += __shfl_xor(acc, 1, 64);
      const float qk = acc + hk * ri;
      qhist[k] = qk;
      const int nv = (k < 5) ? (k + 2) : 4;
      if (k < 5) {
#pragma unroll
        for (int v = 0; v < 6; ++v)
          if ((v & 1) == h && v < nv)
            dp[v][i] = (v <= k) ? gk * qhist[v] : ri * gk;
      } else {
        if (h == 0) { dp[0][i] = gk * qk;  dp[2][i] = wi * gk; }
        else        { dp[1][i] = ri * gk;  dp[3][i] = qk * (1.0f / 256.0f); }
      }
      __syncthreads();  // B
      if (wave < nv) {
        float4 v4 = ((const float4*)&dp[wave][0])[lane];
        float r_ = (v4.x + v4.y) + (v4.z + v4.w);
        r_ = wred_sum(r_);
        if (lane == 0) dres_s[wave] = r_;
      }
      __syncthreads();  // C
      if (k < 5) {
        float dres[6];
#pragma unroll
        for (int v = 0; v < 6; ++v) if (v < nv) dres[v] = rfl(dres_s[v]);
        const float xmmk = dres[k + 1] + hk * XM2;
        const float tki = ETA * ri + KAPPA * qk;
        float sc = alpha * tki;
#pragma unroll
        for (int jj = 0; jj < 4; ++jj)
          if (jj < k) {
            const float MMjk = dres[jj] + hk * xmm[jj];
            const float CCjk = (ETA * ETA) * XM2 + (ETA * KAPPA) * (xmm[jj] + xmmk) +
                               (KAPPA * KAPPA) * MMjk;
            sc += bmat[jj] * CCjk;
          }
        const float MMkk = dres[k] + hk * xmmk;
        const float CCkk = (ETA * ETA) * XM2 + 2.f * (ETA * KAPPA) * xmmk +
                           (KAPPA * KAPPA) * MMkk;
        const float n2 = fmaxf(AA * AA + 2.f * AA * sc + CCkk, 0.f);
        const float inv = 1.0f / (sqrtf(n2) + 1e-10f);
#pragma unroll
        for (int jj = 0; jj < 4; ++jj) if (jj < k) bmat[jj] *= AA * inv;
        bmat[k] = inv; alpha *= AA * inv; xmm[k] = xmmk;
#pragma unroll
        for (int v = 0; v < 5; ++v)
          if ((v & 1) == h && v <= k) dp[v][i] = bmat[v];
        __syncthreads();  // D
        if (wave <= k) {
          float4 v4 = ((const float4*)&dp[wave][0])[lane];
          float r_ = (v4.x + v4.y) + (v4.z + v4.w);
          r_ = wred_sum(r_);
          if (lane == 0) bbar_s[wave] = r_ * (1.0f / 256.0f);
        }
        __syncthreads();  // E
#pragma unroll
        for (int l = 0; l < 5; ++l) if (l <= k) bbar[l] = rfl(bbar_s[l]);
      } else {
        const float A5 = rfl(dres_s[0]);   // <g5, q5>
        const float B5 = rfl(dres_s[1]);   // <r, g5>
        const float C5 = rfl(dres_s[2]);   // <w, g5>
        const float mq5 = rfl(dres_s[3]);  // mean(q5)
        const float h5 = hk, g5 = gk, q5 = qk;
        const float xmm5 = B5 + h5 * XM2;
        const float m52 = A5 + h5 * xmm5;
        const float cmm5 = C5 + h5 * (dotxm + dec * mm2);
        const float lamc = dec * (1.0f + od * h5);
        Zi = lamc * Zi + od * g5;
        yi = lamc * yi + od * h5 * x_c;
        wi = dec * wi + od * q5;
        mm2 = fmaxf(dec * dec * mm2 + 2.f * dec * od * cmm5 + od * od * m52, 0.f);
        mw = dec * mw + od * mq5;
        if (h == 0) {
          ALS[(size_t)t * 256 + i] = alpha;
          BETS[(size_t)1 * (SEQ * 256) + (size_t)t * 256 + i] = bmat[1];
          BETS[(size_t)3 * (SEQ * 256) + (size_t)t * 256 + i] = bmat[3];
          dp[0][i] = bx_n * Zi + x_n * yi;  // next step's <x, mem>
        } else {
          BETS[(size_t)0 * (SEQ * 256) + (size_t)t * 256 + i] = bmat[0];
          BETS[(size_t)2 * (SEQ * 256) + (size_t)t * 256 + i] = bmat[2];
          BETS[(size_t)4 * (SEQ * 256) + (size_t)t * 256 + i] = bmat[4];
          dp[1][i] = bx_n;                  // next step's mean(bx)
        }
        __syncthreads();  // D5
        if (wave < 2) {
          float4 v4 = ((const float4*)&dp[wave][0])[lane];
          float r_ = (v4.x + v4.y) + (v4.z + v4.w);
          r_ = wred_sum(r_);
          if (lane == 0) dres_s[4 + wave] = (wave == 0) ? r_ : r_ * (1.0f / 256.0f);
        }
        __syncthreads();  // E5
        dotxm = rfl(dres_s[4]);
        mbx_c = rfl(dres_s[5]);
      }
    }
    x_c = x_n; bx_c = bx_n; x2_c = x2_n;
  }
}

// ---------------- K15: materialize xm and c_0..c_4 per step ----------------
__global__ void k15_cvec(const float* __restrict__ B, float* __restrict__ ws) {
  const float* ZS = ws + WS_ZS;
  const float* YS = ws + WS_YS;
  const float* GS = ws + WS_GS;
  const float* HS = ws + WS_HS;
  const float* M0 = ws + WS_M0;
  float* CT = ws + WS_CT;
  const int t = blockIdx.x, d = threadIdx.x;
  __shared__ float zs[256], g1[256], g2[256], g3[256], g4[256];
  zs[d] = ZS[(size_t)t * 256 + d];
  g1[d] = GS[0 * (SEQ * 256) + (size_t)t * 256 + d];
  g2[d] = GS[1 * (SEQ * 256) + (size_t)t * 256 + d];
  g3[d] = GS[2 * (SEQ * 256) + (size_t)t * 256 + d];
  g4[d] = GS[3 * (SEQ * 256) + (size_t)t * 256 + d];
  __syncthreads();
  float xa = 0.f, b1 = 0.f, b2 = 0.f, b3 = 0.f, b4 = 0.f;
  for (int ii = 0; ii < 256; ++ii) {
    const float Bv = B[(size_t)ii * 256 + d];
    xa = fmaf(zs[ii], Bv, xa);
    b1 = fmaf(g1[ii], Bv, b1);
    b2 = fmaf(g2[ii], Bv, b2);
    b3 = fmaf(g3[ii], Bv, b3);
    b4 = fmaf(g4[ii], Bv, b4);
  }
  const float xm = YS[(size_t)t * 256 + d] + xa;
  float* ctt = CT + (size_t)t * 1280;
  ctt[0 * 256 + d] = ETA * xm + KAPPA * M0[d];
  const float h1 = HS[0 * SEQ + t], h2 = HS[1 * SEQ + t];
  const float h3 = HS[2 * SEQ + t], h4 = HS[3 * SEQ + t];
  ctt[1 * 256 + d] = (ETA + KAPPA * h1) * xm + KAPPA * b1;
  ctt[2 * 256 + d] = (ETA + KAPPA * h2) * xm + KAPPA * b2;
  ctt[3 * 256 + d] = (ETA + KAPPA * h3) * xm + KAPPA * b3;
  ctt[4 * 256 + d] = (ETA + KAPPA * h4) * xm + KAPPA * b4;
}

// ---------------- K2: per-step rho -> eigenvalues ----------------
__global__ __launch_bounds__(1024, 4) void k2_eig(
    const float* __restrict__ B, const float* __restrict__ ws,
    float* __restrict__ out) {
  const int t = blockIdx.x;
  const int tid = threadIdx.x;
  const int lane = tid & 63, wid = tid >> 6;
  const float* CT = ws + WS_CT + (size_t)t * 1280;
  const float* ALS = ws + WS_ALS + (size_t)t * 256;
  const float* BETS = ws + WS_BETS;

  __shared__ __align__(16) unsigned char bigbuf[135168];  // sT fp16 [256][264] / packed rho fp32
  _Float16* sT = (_Float16*)bigbuf;
  float* pk = (float*)bigbuf;
  __shared__ __align__(16) float ct[1280];
  __shared__ float vx[256], pv[256], qv[256];
  __shared__ float dd[256], ee[256], e2[256], lamv[256];
  __shared__ float red[16];

  for (int idx = tid; idx < 1280; idx += 1024) ct[idx] = CT[idx];
  __syncthreads();

  // --- regenerate s5 rows, store transposed fp16 ---
  {
    const int r = tid >> 2, q = tid & 3;
    const float al = ALS[r];
    const float be0 = BETS[(size_t)0 * (SEQ * 256) + (size_t)t * 256 + r];
    const float be1 = BETS[(size_t)1 * (SEQ * 256) + (size_t)t * 256 + r];
    const float be2 = BETS[(size_t)2 * (SEQ * 256) + (size_t)t * 256 + r];
    const float be3 = BETS[(size_t)3 * (SEQ * 256) + (size_t)t * 256 + r];
    const float be4 = BETS[(size_t)4 * (SEQ * 256) + (size_t)t * 256 + r];
#pragma unroll
    for (int j4 = 0; j4 < 16; ++j4) {
      const int d0 = q * 64 + j4 * 4;
      const float4 Bv = *(const float4*)&B[(size_t)r * 256 + d0];
      const float4 c0 = *(const float4*)&ct[0 * 256 + d0];
      const float4 c1 = *(const float4*)&ct[1 * 256 + d0];
      const float4 c2 = *(const float4*)&ct[2 * 256 + d0];
      const float4 c3 = *(const float4*)&ct[3 * 256 + d0];
      const float4 c4 = *(const float4*)&ct[4 * 256 + d0];
      const float s0 = al * Bv.x + be0 * c0.x + be1 * c1.x + be2 * c2.x + be3 * c3.x + be4 * c4.x;
      const float s1 = al * Bv.y + be0 * c0.y + be1 * c1.y + be2 * c2.y + be3 * c3.y + be4 * c4.y;
      const float s2 = al * Bv.z + be0 * c0.z + be1 * c1.z + be2 * c2.z + be3 * c3.z + be4 * c4.z;
      const float s3 = al * Bv.w + be0 * c0.w + be1 * c1.w + be2 * c2.w + be3 * c3.w + be4 * c4.w;
      sT[(size_t)(d0 + 0) * 264 + r] = (_Float16)s0;
      sT[(size_t)(d0 + 1) * 264 + r] = (_Float16)s1;
      sT[(size_t)(d0 + 2) * 264 + r] = (_Float16)s2;
      sT[(size_t)(d0 + 3) * 264 + r] = (_Float16)s3;
    }
  }
  __syncthreads();

  // --- rho = sT * sT^T / 256 via MFMA f16 (4x4 tiles of 16x16 per wave) ---
  f32x4 acc[4][4];
#pragma unroll
  for (int ti = 0; ti < 4; ++ti)
#pragma unroll
    for (int tj = 0; tj < 4; ++tj) {
      f32x4 z = {0.f, 0.f, 0.f, 0.f};
      acc[ti][tj] = z;
    }
  {
    const int Ib = (wid >> 2) * 4, Jb = (wid & 3) * 4;
    const int mr = lane & 15, kg = lane >> 4;  // A[m=lane&15][k=(lane>>4)*8+j]
#pragma unroll 1
    for (int kb = 0; kb < 8; ++kb) {
      const int ko = kb * 32 + kg * 8;
      f16x8 aF[4], bF[4];
#pragma unroll
      for (int ti = 0; ti < 4; ++ti)
        aF[ti] = *(const f16x8*)&sT[(size_t)((Ib + ti) * 16 + mr) * 264 + ko];
#pragma unroll
      for (int tj = 0; tj < 4; ++tj)
        bF[tj] = *(const f16x8*)&sT[(size_t)((Jb + tj) * 16 + mr) * 264 + ko];
#pragma unroll
      for (int ti = 0; ti < 4; ++ti)
#pragma unroll
        for (int tj = 0; tj < 4; ++tj)
          acc[ti][tj] = __builtin_amdgcn_mfma_f32_16x16x32_f16(aF[ti], bF[tj], acc[ti][tj], 0, 0, 0);
    }
  }
  __syncthreads();  // all fragment reads from sT complete before aliasing writes
  {
    const int Ib = (wid >> 2) * 4, Jb = (wid & 3) * 4;
    const int cn = lane & 15, rg = lane >> 4;  // C/D: col=lane&15, row=(lane>>4)*4+reg
#pragma unroll
    for (int ti = 0; ti < 4; ++ti)
#pragma unroll
      for (int tj = 0; tj < 4; ++tj) {
        const int C = (Jb + tj) * 16 + cn;
        const int Rb = (Ib + ti) * 16 + rg * 4;
#pragma unroll
        for (int rr = 0; rr < 4; ++rr) {
          const int R = Rb + rr;
          if (R >= C) pk[R * (R + 1) / 2 + C] = acc[ti][tj][rr] * (1.0f / 256.0f);
        }
      }
  }
  __syncthreads();

  // --- Householder tridiagonalization on packed lower fp32 ---
#pragma unroll 1
  for (int j = 0; j < 254; ++j) {
    const int m = 255 - j;
    const float x0 = pk[(j + 1) * (j + 2) / 2 + j];
    float ps = 0.f;
    if (tid < m) {
      const int gr = j + 1 + tid;
      const float xv_ = pk[gr * (gr + 1) / 2 + j];
      vx[tid] = xv_;
      ps = xv_ * xv_;
    }
    ps = wred_sum(ps);
    if (lane == 0) red[wid] = ps;
    __syncthreads();  // T1
    float sig2 = 0.f;
#pragma unroll
    for (int w = 0; w < 16; ++w) sig2 += red[w];
    const float sig = sqrtf(sig2);
    const float sg = (x0 >= 0.f) ? 1.f : -1.f;
    const bool live = (sig2 > 1e-26f);
    const float beta = live ? (1.0f / (sig * (sig + fabsf(x0)))) : 0.f;
    const float v0 = live ? (x0 + sg * sig) : 0.f;
    if (tid == 0) {
      dd[j] = pk[j * (j + 1) / 2 + j];
      ee[j] = live ? (-sg * sig) : x0;
      vx[0] = v0;
    }
    __syncthreads();  // T2
    // pv = A22 * v (symmetric packed matvec; quad of threads per row)
    {
      const int ri_ = tid >> 2, qd = tid & 3;
      float acc2 = 0.f;
      if (ri_ < m) {
        const int gr = j + 1 + ri_;
        const int c0 = (m * qd) >> 2, c1 = (m * (qd + 1)) >> 2;
        const int rowbase = gr * (gr + 1) / 2 + (j + 1);
        const int clend = min(c1, ri_ + 1);
        for (int c = c0; c < clend; ++c) acc2 = fmaf(pk[rowbase + c], vx[c], acc2);
        const int cu = max(c0, ri_ + 1);
        if (cu < c1) {
          int gc = j + 1 + cu;
          int ub = gc * (gc + 1) / 2 + gr;
          int stp = gc + 1;
          for (int c = cu; c < c1; ++c) { acc2 = fmaf(pk[ub], vx[c], acc2); ub += stp; ++stp; }
        }
      }
      acc2 += __shfl_xor(acc2, 1, 64);
      acc2 += __shfl_xor(acc2, 2, 64);
      float vpp = 0.f;
      if ((tid & 3) == 0 && (tid >> 2) < m) { pv[tid >> 2] = acc2; vpp = acc2 * vx[tid >> 2]; }
      vpp = wred_sum(vpp);
      if (lane == 0) red[wid] = vpp;
    }
    __syncthreads();  // T3
    float vtp = 0.f;
#pragma unroll
    for (int w = 0; w < 16; ++w) vtp += red[w];
    const float gamma = 0.5f * beta * beta * vtp;
    if (tid < m) qv[tid] = beta * pv[tid] - gamma * vx[tid];
    __syncthreads();  // T4
    // rank-2 update A22 -= v q^T + q v^T (lower packed, paired rows for balance)
    {
      const int Q = tid >> 2, qd = tid & 3;
      const int i2 = m - 1 - Q;
      if (Q <= i2 && Q < m) {
        {
          const int gr = j + 1 + Q;
          const int rb = gr * (gr + 1) / 2 + (j + 1);
          const float vi = vx[Q], qi = qv[Q];
          const int cs = (qd * (Q + 1)) >> 2, ce = ((qd + 1) * (Q + 1)) >> 2;
          for (int c = cs; c < ce; ++c) pk[rb + c] -= vi * qv[c] + qi * vx[c];
        }
        if (i2 > Q) {
          const int gr = j + 1 + i2;
          const int rb = gr * (gr + 1) / 2 + (j + 1);
          const float vi = vx[i2], qi = qv[i2];
          const int cs = (qd * (i2 + 1)) >> 2, ce = ((qd + 1) * (i2 + 1)) >> 2;
          for (int c = cs; c < ce; ++c) pk[rb + c] -= vi * qv[c] + qi * vx[c];
        }
      }
    }
    __syncthreads();  // T5
  }
  if (tid == 0) {
    dd[254] = pk[254 * 255 / 2 + 254];
    dd[255] = pk[255 * 256 / 2 + 255];
    ee[254] = pk[255 * 256 / 2 + 254];
    ee[255] = 0.f;
  }
  __syncthreads();
  if (tid < 256) e2[tid] = ee[tid] * ee[tid];
  __syncthreads();
  // Gershgorin bounds
  float glo = 1e30f, ghi = -1e30f;
  if (tid < 256) {
    const float rad = fabsf(ee[tid]) + ((tid > 0) ? fabsf(ee[tid - 1]) : 0.f);
    glo = dd[tid] - rad;
    ghi = dd[tid] + rad;
  }
  {
    float v = wred_min(glo);
    if (lane == 0) red[wid] = v;
    __syncthreads();
    float lo0 = 1e30f;
#pragma unroll
    for (int w = 0; w < 16; ++w) lo0 = fminf(lo0, red[w]);
    __syncthreads();
    v = wred_max(ghi);
    if (lane == 0) red[wid] = v;
    __syncthreads();
    float hi0 = -1e30f;
#pragma unroll
    for (int w = 0; w < 16; ++w) hi0 = fmaxf(hi0, red[w]);
    lo0 -= 1e-3f + 1e-3f * fabsf(lo0);
    hi0 += 1e-3f + 1e-3f * fabsf(hi0);
    // Sturm bisection: thread k -> k-th smallest eigenvalue
    if (tid < 256) {
      float lo = lo0, hi = hi0;
      for (int it = 0; it < 21; ++it) {
        const float x = 0.5f * (lo + hi);
        int cnt = 0;
        float qq = dd[0] - x;
        cnt += (qq < 0.f);
        for (int ii = 1; ii < 256; ++ii) {
          float dn = qq;
          if (fabsf(dn) < 1e-25f) dn = (dn < 0.f) ? -1e-25f : 1e-25f;
          qq = (dd[ii] - x) - e2[ii - 1] * __builtin_amdgcn_rcpf(dn);
          cnt += (qq < 0.f);
        }
        if (cnt >= tid + 1) hi = x; else lo = x;
      }
      lamv[tid] = fmaxf(0.5f * (lo + hi), 0.f);
    }
  }
  __syncthreads();
  float sv = (tid < 256) ? lamv[tid] : 0.f;
  sv = wred_sum(sv);
  if (lane == 0) red[wid] = sv;
  __syncthreads();
  float S = 0.f;
#pragma unroll
  for (int w = 0; w < 16; ++w) S += red[w];
  if (tid < 256) out[(size_t)t * 256 + tid] = lamv[tid] / (S + 1e-10f);
}

extern "C" void kernel_launch(void* const* d_in, const int* in_sizes, int n_in,
                              void* d_out, int out_size, void* d_ws, size_t ws_size,
                              hipStream_t stream) {
  const float* embed = (const float*)d_in[0];
  const float* B = (const float*)d_in[1];
  const float* mdb = (const float*)d_in[2];
  const float* sens = (const float*)d_in[3];
  const int* toks = (const int*)d_in[4];
  float* out = (float*)d_out;
  float* ws = (float*)d_ws;

  k0_gram<<<dim3(256), dim3(256), 0, stream>>>(B, ws);
  k0_m0<<<dim3(1), dim3(256), 0, stream>>>(B, ws);
  k0_bx<<<dim3(SEQ), dim3(256), 0, stream>>>(B, embed, toks, ws);
  k1_seq<<<dim3(1), dim3(512), 0, stream>>>(embed, toks, mdb, sens, ws);
  k15_cvec<<<dim3(SEQ), dim3(256), 0, stream>>>(B, ws);
  k2_eig<<<dim3(SEQ), dim3(1024), 0, stream>>>(B, ws, out);
}